// Round 4
// baseline (305.686 us; speedup 1.0000x reference)
//
#include <hip/hip_runtime.h>
#include <cstdint>

#define NN 100000
#define NE 640000
#define DIN 128
#define DOUT 256
#define LN_EPS 1e-5f
#define NBLK_SCAN 391   // ceil(NN/256)

typedef __attribute__((ext_vector_type(8))) short bf16x8;
typedef __attribute__((ext_vector_type(4))) float f32x4;

// ---- workspace layout (bytes) ----
#define WS_PKL  0u
#define WS_PKR  65536u
#define WS_PKP  131072u
#define WS_XB   196608u                              // [NN][128] bf16 = 25,600,000
#define WS_AGB  (WS_XB + (size_t)NN * DIN * 2)       // [NN][128] bf16
#define WS_CNTI (WS_AGB + (size_t)NN * DIN * 2)      // [NN] int (memset 0 each call)
#define WS_OFFS (WS_CNTI + (size_t)NN * 4)           // [NN+1] int
#define WS_CURS (WS_OFFS + (size_t)(NN + 1) * 4)
#define WS_BS1  (WS_CURS + (size_t)NN * 4)
#define WS_BS2  (WS_BS1 + (size_t)NBLK_SCAN * 4)
#define WS_SRCI (WS_BS2 + (size_t)NBLK_SCAN * 4)     // [NE] int

static __device__ __forceinline__ unsigned short f2bf(float f) {
    unsigned u = __builtin_bit_cast(unsigned, f);
    u += 0x7FFFu + ((u >> 16) & 1u);          // round-to-nearest-even
    return (unsigned short)(u >> 16);
}
static __device__ __forceinline__ float bf2f_lo(unsigned u) {
    return __builtin_bit_cast(float, u << 16);
}
static __device__ __forceinline__ float bf2f_hi(unsigned u) {
    return __builtin_bit_cast(float, u & 0xFFFF0000u);
}

// Pack W [DOUT][DIN] f32 -> bf16 B-fragment layout for mfma_f32_16x16x32_bf16.
__global__ __launch_bounds__(256)
void pack_w_kernel(const float* __restrict__ W, unsigned short* __restrict__ pk) {
    int t2 = blockIdx.x * 256 + threadIdx.x;
    if (t2 >= 4096) return;
    int kt = t2 >> 10;
    int ct = (t2 >> 6) & 15;
    int l  = t2 & 63;
    int n  = ct * 16 + (l & 15);
    int kb = kt * 32 + (l >> 4) * 8;
    const float4* wp = (const float4*)(W + n * DIN + kb);
    float4 a = wp[0], b = wp[1];
    bf16x8 o;
    o[0]=(short)f2bf(a.x); o[1]=(short)f2bf(a.y); o[2]=(short)f2bf(a.z); o[3]=(short)f2bf(a.w);
    o[4]=(short)f2bf(b.x); o[5]=(short)f2bf(b.y); o[6]=(short)f2bf(b.z); o[7]=(short)f2bf(b.w);
    *(bf16x8*)(pk + (size_t)t2 * 8) = o;
}

// x f32 -> xb bf16, 8 elems/thread
__global__ __launch_bounds__(256)
void convert_x_kernel(const float* __restrict__ x, unsigned short* __restrict__ xb) {
    size_t i = (size_t)blockIdx.x * 256 + threadIdx.x;   // one per 8 elems
    if (i >= (size_t)NN * 16) return;
    const float4* xp = (const float4*)x + i * 2;
    float4 a = xp[0], b = xp[1];
    bf16x8 o;
    o[0]=(short)f2bf(a.x); o[1]=(short)f2bf(a.y); o[2]=(short)f2bf(a.z); o[3]=(short)f2bf(a.w);
    o[4]=(short)f2bf(b.x); o[5]=(short)f2bf(b.y); o[6]=(short)f2bf(b.z); o[7]=(short)f2bf(b.w);
    *(bf16x8*)(xb + i * 8) = o;
}

// ---- CSR build ----
__global__ __launch_bounds__(256)
void count_kernel(const int* __restrict__ ei, int* __restrict__ cnt) {
    int e = blockIdx.x * 256 + threadIdx.x;
    if (e >= NE) return;
    atomicAdd(&cnt[ei[NE + e]], 1);
}

__global__ __launch_bounds__(256)
void scan_block_sums(const int* __restrict__ cnt, int* __restrict__ blockSums) {
    __shared__ int red[256];
    int i = blockIdx.x * 256 + threadIdx.x;
    red[threadIdx.x] = (i < NN) ? cnt[i] : 0;
    __syncthreads();
    for (int o = 128; o > 0; o >>= 1) {
        if (threadIdx.x < o) red[threadIdx.x] += red[threadIdx.x + o];
        __syncthreads();
    }
    if (threadIdx.x == 0) blockSums[blockIdx.x] = red[0];
}

__global__ __launch_bounds__(512)
void scan_partials(const int* __restrict__ blockSums, int* __restrict__ bsumScan) {
    __shared__ int s[512];
    int t = threadIdx.x;
    int v = (t < NBLK_SCAN) ? blockSums[t] : 0;
    s[t] = v; __syncthreads();
    for (int o = 1; o < 512; o <<= 1) {
        int add = (t >= o) ? s[t - o] : 0;
        __syncthreads();
        s[t] += add;
        __syncthreads();
    }
    if (t < NBLK_SCAN) bsumScan[t] = s[t] - v;   // exclusive
}

__global__ __launch_bounds__(256)
void scan_final(const int* __restrict__ cnt, const int* __restrict__ bsumScan,
                int* __restrict__ offsets, int* __restrict__ cursor) {
    __shared__ int s[256];
    int t = threadIdx.x;
    int i = blockIdx.x * 256 + t;
    int v = (i < NN) ? cnt[i] : 0;
    s[t] = v; __syncthreads();
    for (int o = 1; o < 256; o <<= 1) {
        int add = (t >= o) ? s[t - o] : 0;
        __syncthreads();
        s[t] += add;
        __syncthreads();
    }
    int excl = s[t] - v + bsumScan[blockIdx.x];
    if (i < NN) {
        offsets[i] = excl;
        cursor[i]  = excl;
        if (i == NN - 1) offsets[NN] = excl + v;
    }
}

__global__ __launch_bounds__(256)
void scatter_kernel(const int* __restrict__ ei, int* __restrict__ cursor,
                    int* __restrict__ srcIdx) {
    int e = blockIdx.x * 256 + threadIdx.x;
    if (e >= NE) return;
    int src = ei[e], dst = ei[NE + e];
    int pos = atomicAdd(&cursor[dst], 1);
    srcIdx[pos] = src;
}

// one wave per node: gather bf16 neighbor rows, mean in f32, write bf16 agg
__global__ __launch_bounds__(256)
void csr_aggregate(const unsigned short* __restrict__ xb, const int* __restrict__ srcIdx,
                   const int* __restrict__ offsets, unsigned short* __restrict__ agb) {
    int w = threadIdx.x >> 6, l = threadIdx.x & 63;
    int node = blockIdx.x * 4 + w;
    if (node >= NN) return;
    int beg = offsets[node], end = offsets[node + 1];
    float sx = 0.0f, sy = 0.0f;
    for (int j = beg; j < end; ++j) {
        int s = srcIdx[j];
        unsigned u = *(const unsigned*)(xb + (size_t)s * DIN + l * 2);
        sx += bf2f_lo(u);
        sy += bf2f_hi(u);
    }
    float iv = 1.0f / fmaxf((float)(end - beg), 1.0f);
    unsigned short a0 = f2bf(sx * iv), a1 = f2bf(sy * iv);
    *(unsigned*)(agb + (size_t)node * DIN + l * 2) = ((unsigned)a1 << 16) | a0;
}

// 64 nodes/block, 4 waves; wave w owns cols [w*64, w*64+64).
// Pass1: h = ag@Wl + x@Wr (direct global A-frag loads). Bias+LN+GELU in
// accumulator. Pass2: h += x@Wp (reload x frags from L1). Store.
__global__ __launch_bounds__(256)
void fused_mfma_kernel(const unsigned short* __restrict__ xb,
                       const unsigned short* __restrict__ agb,
                       const unsigned short* __restrict__ pkWl,
                       const unsigned short* __restrict__ pkWr,
                       const unsigned short* __restrict__ pkWp,
                       const float* __restrict__ b_l, const float* __restrict__ gamma,
                       const float* __restrict__ beta, float* __restrict__ out) {
    __shared__ float redS[4][64], redS2[4][64];
    __shared__ float muS[64], rsS[64];

    const int t = threadIdx.x;
    const int w = t >> 6, l = t & 63;
    const int base = blockIdx.x * 64;
    const int rlo = l & 15;
    const int kof = (l >> 4) * 8;

    f32x4 h[4][4];
#pragma unroll
    for (int a = 0; a < 4; ++a)
#pragma unroll
        for (int b = 0; b < 4; ++b) h[a][b] = (f32x4)(0.0f);

    // ---- pass 1: h = ag@Wl + x@Wr ----
#pragma unroll
    for (int kt = 0; kt < 4; ++kt) {
        bf16x8 ax[4], ag[4];
#pragma unroll
        for (int rt = 0; rt < 4; ++rt) {
            int r = base + rt * 16 + rlo;
            r = (r < NN) ? r : (NN - 1);
            size_t ao = (size_t)r * DIN + kt * 32 + kof;
            ax[rt] = *(const bf16x8*)(xb + ao);
            ag[rt] = *(const bf16x8*)(agb + ao);
        }
#pragma unroll
        for (int ct = 0; ct < 4; ++ct) {
            size_t boff = ((size_t)(kt * 16 + w * 4 + ct) * 64 + l) * 8;
            bf16x8 bl = *(const bf16x8*)(pkWl + boff);
            bf16x8 br = *(const bf16x8*)(pkWr + boff);
#pragma unroll
            for (int rt = 0; rt < 4; ++rt) {
                h[rt][ct] = __builtin_amdgcn_mfma_f32_16x16x32_bf16(ag[rt], bl, h[rt][ct], 0, 0, 0);
                h[rt][ct] = __builtin_amdgcn_mfma_f32_16x16x32_bf16(ax[rt], br, h[rt][ct], 0, 0, 0);
            }
        }
    }

    // ---- bias + LN stats ----
    float bl4[4], gm4[4], bt4[4];
#pragma unroll
    for (int ct = 0; ct < 4; ++ct) {
        int n = w * 64 + ct * 16 + rlo;
        bl4[ct] = b_l[n]; gm4[ct] = gamma[n]; bt4[ct] = beta[n];
    }

#pragma unroll
    for (int rt = 0; rt < 4; ++rt) {
        float s[4] = {0, 0, 0, 0}, s2[4] = {0, 0, 0, 0};
#pragma unroll
        for (int ct = 0; ct < 4; ++ct)
#pragma unroll
            for (int j = 0; j < 4; ++j) {
                float v = h[rt][ct][j] + bl4[ct];
                h[rt][ct][j] = v;
                s[j] += v; s2[j] += v * v;
            }
#pragma unroll
        for (int o = 1; o < 16; o <<= 1) {
#pragma unroll
            for (int j = 0; j < 4; ++j) {
                s[j]  += __shfl_xor(s[j], o);
                s2[j] += __shfl_xor(s2[j], o);
            }
        }
        if (rlo == 0) {
#pragma unroll
            for (int j = 0; j < 4; ++j) {
                int row = rt * 16 + (l >> 4) * 4 + j;
                redS[w][row] = s[j]; redS2[w][row] = s2[j];
            }
        }
    }
    __syncthreads();

    if (t < 64) {
        float mu = (redS[0][t] + redS[1][t] + redS[2][t] + redS[3][t]) * (1.0f / DOUT);
        float m2 = (redS2[0][t] + redS2[1][t] + redS2[2][t] + redS2[3][t]) * (1.0f / DOUT);
        float var = m2 - mu * mu;
        muS[t] = mu;
        rsS[t] = rsqrtf(var + LN_EPS);
    }
    __syncthreads();

    // ---- LN + GELU into accumulator ----
#pragma unroll
    for (int rt = 0; rt < 4; ++rt) {
#pragma unroll
        for (int j = 0; j < 4; ++j) {
            int row = rt * 16 + (l >> 4) * 4 + j;
            float mu = muS[row], rs = rsS[row];
#pragma unroll
            for (int ct = 0; ct < 4; ++ct) {
                float v = h[rt][ct][j];
                float nrm = (v - mu) * rs * gm4[ct] + bt4[ct];
                h[rt][ct][j] = 0.5f * nrm * (1.0f + erff(nrm * 0.70710678118f));
            }
        }
    }

    // ---- pass 2: h += x@Wp ----
#pragma unroll
    for (int kt = 0; kt < 4; ++kt) {
        bf16x8 ax[4];
#pragma unroll
        for (int rt = 0; rt < 4; ++rt) {
            int r = base + rt * 16 + rlo;
            r = (r < NN) ? r : (NN - 1);
            ax[rt] = *(const bf16x8*)(xb + (size_t)r * DIN + kt * 32 + kof);
        }
#pragma unroll
        for (int ct = 0; ct < 4; ++ct) {
            size_t boff = ((size_t)(kt * 16 + w * 4 + ct) * 64 + l) * 8;
            bf16x8 bp = *(const bf16x8*)(pkWp + boff);
#pragma unroll
            for (int rt = 0; rt < 4; ++rt)
                h[rt][ct] = __builtin_amdgcn_mfma_f32_16x16x32_bf16(ax[rt], bp, h[rt][ct], 0, 0, 0);
        }
    }

    // ---- store ----
#pragma unroll
    for (int rt = 0; rt < 4; ++rt) {
#pragma unroll
        for (int j = 0; j < 4; ++j) {
            int row = rt * 16 + (l >> 4) * 4 + j;
            int r = base + row;
            if (r >= NN) continue;
#pragma unroll
            for (int ct = 0; ct < 4; ++ct) {
                int n = w * 64 + ct * 16 + rlo;
                out[(size_t)r * DOUT + n] = h[rt][ct][j];
            }
        }
    }
}

extern "C" void kernel_launch(void* const* d_in, const int* in_sizes, int n_in,
                              void* d_out, int out_size, void* d_ws, size_t ws_size,
                              hipStream_t stream) {
    const float* x      = (const float*)d_in[0];
    const int*   ei     = (const int*)d_in[1];
    const float* W_l    = (const float*)d_in[2];
    const float* b_l    = (const float*)d_in[3];
    const float* W_r    = (const float*)d_in[4];
    const float* gamma  = (const float*)d_in[5];
    const float* beta   = (const float*)d_in[6];
    const float* W_proj = (const float*)d_in[7];
    float* out = (float*)d_out;

    char* ws = (char*)d_ws;
    unsigned short* pkWl = (unsigned short*)(ws + WS_PKL);
    unsigned short* pkWr = (unsigned short*)(ws + WS_PKR);
    unsigned short* pkWp = (unsigned short*)(ws + WS_PKP);
    unsigned short* xb   = (unsigned short*)(ws + WS_XB);
    unsigned short* agb  = (unsigned short*)(ws + WS_AGB);
    int*   cntI    = (int*)(ws + WS_CNTI);
    int*   offsets = (int*)(ws + WS_OFFS);
    int*   cursor  = (int*)(ws + WS_CURS);
    int*   bs1     = (int*)(ws + WS_BS1);
    int*   bs2     = (int*)(ws + WS_BS2);
    int*   srcIdx  = (int*)(ws + WS_SRCI);

    hipMemsetAsync(cntI, 0, (size_t)NN * 4, stream);

    pack_w_kernel<<<16, 256, 0, stream>>>(W_l, pkWl);
    pack_w_kernel<<<16, 256, 0, stream>>>(W_r, pkWr);
    pack_w_kernel<<<16, 256, 0, stream>>>(W_proj, pkWp);
    convert_x_kernel<<<(NN * 16 + 255) / 256, 256, 0, stream>>>(x, xb);

    count_kernel<<<(NE + 255) / 256, 256, 0, stream>>>(ei, cntI);
    scan_block_sums<<<NBLK_SCAN, 256, 0, stream>>>(cntI, bs1);
    scan_partials<<<1, 512, 0, stream>>>(bs1, bs2);
    scan_final<<<NBLK_SCAN, 256, 0, stream>>>(cntI, bs2, offsets, cursor);
    scatter_kernel<<<(NE + 255) / 256, 256, 0, stream>>>(ei, cursor, srcIdx);
    csr_aggregate<<<(NN + 3) / 4, 256, 0, stream>>>(xb, srcIdx, offsets, agb);

    fused_mfma_kernel<<<(NN + 63) / 64, 256, 0, stream>>>(
        xb, agb, pkWl, pkWr, pkWp, b_l, gamma, beta, out);
}

// Round 5
// 243.092 us; speedup vs baseline: 1.2575x; 1.2575x over previous
//
#include <hip/hip_runtime.h>
#include <cstdint>

#define NN 100000
#define NE 640000
#define DIN 128
#define DOUT 256
#define LN_EPS 1e-5f
#define CAP 64   // slots per node; P(deg>=64) ~ 1e-45 for Poisson(6.4)

typedef __attribute__((ext_vector_type(8))) short bf16x8;
typedef __attribute__((ext_vector_type(4))) float f32x4;

// ---- workspace layout (bytes) ----
#define WS_PKL  0u
#define WS_PKR  65536u
#define WS_PKP  131072u
#define WS_XB   196608u                              // [NN][128] bf16 = 25.6 MB
#define WS_AGB  (WS_XB + (size_t)NN * DIN * 2)       // [NN][128] bf16
#define WS_CNTI (WS_AGB + (size_t)NN * DIN * 2)      // [NN] int (memset 0 each call)
#define WS_SLOT (WS_CNTI + (size_t)NN * 4)           // [NN][CAP] int = 25.6 MB

static __device__ __forceinline__ unsigned short f2bf(float f) {
    unsigned u = __builtin_bit_cast(unsigned, f);
    u += 0x7FFFu + ((u >> 16) & 1u);          // round-to-nearest-even
    return (unsigned short)(u >> 16);
}
static __device__ __forceinline__ float bf2f_lo(unsigned u) {
    return __builtin_bit_cast(float, u << 16);
}
static __device__ __forceinline__ float bf2f_hi(unsigned u) {
    return __builtin_bit_cast(float, u & 0xFFFF0000u);
}

// async global->LDS, 16B per lane; lds base must be wave-uniform, g is per-lane
static __device__ __forceinline__ void async16(void* lds, const void* g) {
    __builtin_amdgcn_global_load_lds(
        (const __attribute__((address_space(1))) unsigned*)g,
        (__attribute__((address_space(3))) unsigned*)lds, 16, 0, 0);
}

// ---- one prep kernel: pack 3 weights + convert x->bf16 + scatter edges ----
// blocks [0,48): pack (b>>4 selects matrix); [48,6298): convert; [6298,8798): scatter
__global__ __launch_bounds__(256)
void prep_kernel(const float* __restrict__ Wl, const float* __restrict__ Wr,
                 const float* __restrict__ Wp, const float* __restrict__ x,
                 const int* __restrict__ ei,
                 unsigned short* __restrict__ pkWl, unsigned short* __restrict__ pkWr,
                 unsigned short* __restrict__ pkWp,
                 unsigned short* __restrict__ xb,
                 int* __restrict__ cntI, int* __restrict__ slots) {
    const int b = blockIdx.x, tid = threadIdx.x;
    if (b < 48) {
        // pack W [DOUT][DIN] f32 -> bf16 B-fragment layout (16x16x32)
        int m = b >> 4;
        const float* W = (m == 0) ? Wl : (m == 1) ? Wr : Wp;
        unsigned short* pk = (m == 0) ? pkWl : (m == 1) ? pkWr : pkWp;
        int t2 = (b & 15) * 256 + tid;            // 0..4095
        int kt = t2 >> 10;
        int ct = (t2 >> 6) & 15;
        int l  = t2 & 63;
        int n  = ct * 16 + (l & 15);
        int kb = kt * 32 + (l >> 4) * 8;
        const float4* wp = (const float4*)(W + n * DIN + kb);
        float4 a = wp[0], c = wp[1];
        bf16x8 o;
        o[0]=(short)f2bf(a.x); o[1]=(short)f2bf(a.y); o[2]=(short)f2bf(a.z); o[3]=(short)f2bf(a.w);
        o[4]=(short)f2bf(c.x); o[5]=(short)f2bf(c.y); o[6]=(short)f2bf(c.z); o[7]=(short)f2bf(c.w);
        *(bf16x8*)(pk + (size_t)t2 * 8) = o;
    } else if (b < 6298) {
        // convert x f32 -> bf16, 8 elems/thread; (6250*256) == NN*16 exactly
        size_t i = (size_t)(b - 48) * 256 + tid;
        const float4* xp = (const float4*)x + i * 2;
        float4 a = xp[0], c = xp[1];
        bf16x8 o;
        o[0]=(short)f2bf(a.x); o[1]=(short)f2bf(a.y); o[2]=(short)f2bf(a.z); o[3]=(short)f2bf(a.w);
        o[4]=(short)f2bf(c.x); o[5]=(short)f2bf(c.y); o[6]=(short)f2bf(c.z); o[7]=(short)f2bf(c.w);
        *(bf16x8*)(xb + i * 8) = o;
    } else {
        // scatter edges into per-destination slot table; (2500*256) == NE exactly
        int e = (b - 6298) * 256 + tid;
        int src = ei[e], dst = ei[NE + e];
        int pos = atomicAdd(&cntI[dst], 1);
        if (pos < CAP) slots[(size_t)dst * CAP + pos] = src;
    }
}

// one wave per node: gather bf16 neighbor rows from slot table, mean, write bf16
__global__ __launch_bounds__(256)
void slot_aggregate(const unsigned short* __restrict__ xb, const int* __restrict__ slots,
                    const int* __restrict__ cntI, unsigned short* __restrict__ agb) {
    int w = threadIdx.x >> 6, l = threadIdx.x & 63;
    int node = blockIdx.x * 4 + w;
    if (node >= NN) return;
    int c = cntI[node];
    c = (c < CAP) ? c : CAP;
    const int* sl = slots + (size_t)node * CAP;
    float sx = 0.0f, sy = 0.0f;
    for (int j = 0; j < c; ++j) {
        int s = sl[j];
        unsigned u = *(const unsigned*)(xb + (size_t)s * DIN + l * 2);
        sx += bf2f_lo(u);
        sy += bf2f_hi(u);
    }
    float iv = 1.0f / fmaxf((float)c, 1.0f);
    unsigned short a0 = f2bf(sx * iv), a1 = f2bf(sy * iv);
    *(unsigned*)(agb + (size_t)node * DIN + l * 2) = ((unsigned)a1 << 16) | a0;
}

// 64 nodes/block, 4 waves; wave w owns cols [w*64, w*64+64) and stages row-quad rt=w.
// Stage bf16 A-frags into LDS via global_load_lds (no VGPR round-trip).
// Pass1: h = ag@Wl + x@Wr. Bias+LN+GELU in accumulator. Pass2: h += x@Wp. Store.
__global__ __launch_bounds__(256, 4)
void fused_mfma_kernel(const unsigned short* __restrict__ xb,
                       const unsigned short* __restrict__ agb,
                       const unsigned short* __restrict__ pkWl,
                       const unsigned short* __restrict__ pkWr,
                       const unsigned short* __restrict__ pkWp,
                       const float* __restrict__ b_l, const float* __restrict__ gamma,
                       const float* __restrict__ beta, float* __restrict__ out) {
    __shared__ unsigned short xsPk[4 * 4 * 64 * 8];   // [rt][kt][l][8] bf16, 16 KB
    __shared__ unsigned short agPk[4 * 4 * 64 * 8];
    __shared__ float redS[4][64], redS2[4][64];
    __shared__ float muS[64], rsS[64];

    const int t = threadIdx.x;
    const int w = t >> 6, l = t & 63;
    const int base = blockIdx.x * 64;
    const int rlo = l & 15;
    const int kof = (l >> 4) * 8;

    // ---- stage: wave w loads row-quad rt=w for x and agg ----
    {
        int r = base + w * 16 + rlo;
        if (r >= NN) r = NN - 1;                       // dup row; discarded on store
        const unsigned short* gx = xb  + (size_t)r * DIN + kof;
        const unsigned short* ga = agb + (size_t)r * DIN + kof;
#pragma unroll
        for (int kt = 0; kt < 4; ++kt) {
            async16(&xsPk[(size_t)((w * 4 + kt) * 64) * 8], gx + kt * 32);
            async16(&agPk[(size_t)((w * 4 + kt) * 64) * 8], ga + kt * 32);
        }
    }
    __syncthreads();   // drains vmcnt before ds_read

    f32x4 h[4][4];
#pragma unroll
    for (int a = 0; a < 4; ++a)
#pragma unroll
        for (int b = 0; b < 4; ++b) h[a][b] = (f32x4)(0.0f);

    // ---- pass 1: h = ag@Wl + x@Wr ----
#pragma unroll
    for (int kt = 0; kt < 4; ++kt) {
        bf16x8 ax[4], ag[4];
#pragma unroll
        for (int rt = 0; rt < 4; ++rt) {
            size_t off = ((size_t)(rt * 4 + kt) * 64 + l) * 8;
            ax[rt] = *(const bf16x8*)&xsPk[off];
            ag[rt] = *(const bf16x8*)&agPk[off];
        }
#pragma unroll
        for (int ct = 0; ct < 4; ++ct) {
            size_t boff = ((size_t)(kt * 16 + w * 4 + ct) * 64 + l) * 8;
            bf16x8 bl = *(const bf16x8*)(pkWl + boff);
            bf16x8 br = *(const bf16x8*)(pkWr + boff);
#pragma unroll
            for (int rt = 0; rt < 4; ++rt) {
                h[rt][ct] = __builtin_amdgcn_mfma_f32_16x16x32_bf16(ag[rt], bl, h[rt][ct], 0, 0, 0);
                h[rt][ct] = __builtin_amdgcn_mfma_f32_16x16x32_bf16(ax[rt], br, h[rt][ct], 0, 0, 0);
            }
        }
    }

    // ---- bias + LN stats ----
    float bl4[4], gm4[4], bt4[4];
#pragma unroll
    for (int ct = 0; ct < 4; ++ct) {
        int n = w * 64 + ct * 16 + rlo;
        bl4[ct] = b_l[n]; gm4[ct] = gamma[n]; bt4[ct] = beta[n];
    }

#pragma unroll
    for (int rt = 0; rt < 4; ++rt) {
        float s[4] = {0, 0, 0, 0}, s2[4] = {0, 0, 0, 0};
#pragma unroll
        for (int ct = 0; ct < 4; ++ct)
#pragma unroll
            for (int j = 0; j < 4; ++j) {
                float v = h[rt][ct][j] + bl4[ct];
                h[rt][ct][j] = v;
                s[j] += v; s2[j] += v * v;
            }
#pragma unroll
        for (int o = 1; o < 16; o <<= 1) {
#pragma unroll
            for (int j = 0; j < 4; ++j) {
                s[j]  += __shfl_xor(s[j], o);
                s2[j] += __shfl_xor(s2[j], o);
            }
        }
        if (rlo == 0) {
#pragma unroll
            for (int j = 0; j < 4; ++j) {
                int row = rt * 16 + (l >> 4) * 4 + j;
                redS[w][row] = s[j]; redS2[w][row] = s2[j];
            }
        }
    }
    __syncthreads();

    if (t < 64) {
        float mu = (redS[0][t] + redS[1][t] + redS[2][t] + redS[3][t]) * (1.0f / DOUT);
        float m2 = (redS2[0][t] + redS2[1][t] + redS2[2][t] + redS2[3][t]) * (1.0f / DOUT);
        float var = m2 - mu * mu;
        muS[t] = mu;
        rsS[t] = rsqrtf(var + LN_EPS);
    }
    __syncthreads();

    // ---- LN + GELU into accumulator ----
#pragma unroll
    for (int rt = 0; rt < 4; ++rt) {
#pragma unroll
        for (int j = 0; j < 4; ++j) {
            int row = rt * 16 + (l >> 4) * 4 + j;
            float mu = muS[row], rs = rsS[row];
#pragma unroll
            for (int ct = 0; ct < 4; ++ct) {
                float v = h[rt][ct][j];
                float nrm = (v - mu) * rs * gm4[ct] + bt4[ct];
                h[rt][ct][j] = 0.5f * nrm * (1.0f + erff(nrm * 0.70710678118f));
            }
        }
    }

    // ---- pass 2: h += x@Wp (A-frags re-read from LDS) ----
#pragma unroll
    for (int kt = 0; kt < 4; ++kt) {
        bf16x8 ax[4];
#pragma unroll
        for (int rt = 0; rt < 4; ++rt) {
            size_t off = ((size_t)(rt * 4 + kt) * 64 + l) * 8;
            ax[rt] = *(const bf16x8*)&xsPk[off];
        }
#pragma unroll
        for (int ct = 0; ct < 4; ++ct) {
            size_t boff = ((size_t)(kt * 16 + w * 4 + ct) * 64 + l) * 8;
            bf16x8 bp = *(const bf16x8*)(pkWp + boff);
#pragma unroll
            for (int rt = 0; rt < 4; ++rt)
                h[rt][ct] = __builtin_amdgcn_mfma_f32_16x16x32_bf16(ax[rt], bp, h[rt][ct], 0, 0, 0);
        }
    }

    // ---- store ----
#pragma unroll
    for (int rt = 0; rt < 4; ++rt) {
#pragma unroll
        for (int j = 0; j < 4; ++j) {
            int row = rt * 16 + (l >> 4) * 4 + j;
            int r = base + row;
            if (r >= NN) continue;
#pragma unroll
            for (int ct = 0; ct < 4; ++ct) {
                int n = w * 64 + ct * 16 + rlo;
                out[(size_t)r * DOUT + n] = h[rt][ct][j];
            }
        }
    }
}

extern "C" void kernel_launch(void* const* d_in, const int* in_sizes, int n_in,
                              void* d_out, int out_size, void* d_ws, size_t ws_size,
                              hipStream_t stream) {
    const float* x      = (const float*)d_in[0];
    const int*   ei     = (const int*)d_in[1];
    const float* W_l    = (const float*)d_in[2];
    const float* b_l    = (const float*)d_in[3];
    const float* W_r    = (const float*)d_in[4];
    const float* gamma  = (const float*)d_in[5];
    const float* beta   = (const float*)d_in[6];
    const float* W_proj = (const float*)d_in[7];
    float* out = (float*)d_out;

    char* ws = (char*)d_ws;
    unsigned short* pkWl = (unsigned short*)(ws + WS_PKL);
    unsigned short* pkWr = (unsigned short*)(ws + WS_PKR);
    unsigned short* pkWp = (unsigned short*)(ws + WS_PKP);
    unsigned short* xb   = (unsigned short*)(ws + WS_XB);
    unsigned short* agb  = (unsigned short*)(ws + WS_AGB);
    int* cntI  = (int*)(ws + WS_CNTI);
    int* slots = (int*)(ws + WS_SLOT);

    hipMemsetAsync(cntI, 0, (size_t)NN * 4, stream);

    prep_kernel<<<8798, 256, 0, stream>>>(W_l, W_r, W_proj, x, ei,
                                          pkWl, pkWr, pkWp, xb, cntI, slots);

    slot_aggregate<<<(NN + 3) / 4, 256, 0, stream>>>(xb, slots, cntI, agb);

    fused_mfma_kernel<<<(NN + 63) / 64, 256, 0, stream>>>(
        xb, agb, pkWl, pkWr, pkWp, b_l, gamma, beta, out);
}

// Round 6
// 215.249 us; speedup vs baseline: 1.4202x; 1.1294x over previous
//
#include <hip/hip_runtime.h>
#include <cstdint>

#define NN 100000
#define NE 640000
#define DIN 128
#define DOUT 256
#define LN_EPS 1e-5f
#define CAP 64   // slots per node; P(deg>=64) ~ 1e-45 for Poisson(6.4)

typedef __attribute__((ext_vector_type(8))) short bf16x8;
typedef __attribute__((ext_vector_type(4))) float f32x4;

// ---- workspace layout (bytes) ----
#define WS_PKL  0u
#define WS_PKR  65536u
#define WS_PKP  131072u
#define WS_XB   196608u                              // [NN][128] bf16 = 25.6 MB
#define WS_AGB  (WS_XB + (size_t)NN * DIN * 2)       // [NN][128] bf16
#define WS_CNTI (WS_AGB + (size_t)NN * DIN * 2)      // [NN] int (memset 0 each call)
#define WS_SLOT (WS_CNTI + (size_t)NN * 4)           // [NN][CAP] int = 25.6 MB

static __device__ __forceinline__ unsigned short f2bf(float f) {
    unsigned u = __builtin_bit_cast(unsigned, f);
    u += 0x7FFFu + ((u >> 16) & 1u);          // round-to-nearest-even
    return (unsigned short)(u >> 16);
}
static __device__ __forceinline__ float bf2f_lo(unsigned u) {
    return __builtin_bit_cast(float, u << 16);
}
static __device__ __forceinline__ float bf2f_hi(unsigned u) {
    return __builtin_bit_cast(float, u & 0xFFFF0000u);
}

// async global->LDS, 16B per lane; lds base must be wave-uniform, g is per-lane
static __device__ __forceinline__ void async16(void* lds, const void* g) {
    __builtin_amdgcn_global_load_lds(
        (const __attribute__((address_space(1))) unsigned*)g,
        (__attribute__((address_space(3))) unsigned*)lds, 16, 0, 0);
}

// ---- one prep kernel: pack 3 weights + convert x->bf16 + scatter edges ----
// blocks [0,48): pack (b>>4 selects matrix); [48,6298): convert; [6298,8798): scatter
__global__ __launch_bounds__(256)
void prep_kernel(const float* __restrict__ Wl, const float* __restrict__ Wr,
                 const float* __restrict__ Wp, const float* __restrict__ x,
                 const int* __restrict__ ei,
                 unsigned short* __restrict__ pkWl, unsigned short* __restrict__ pkWr,
                 unsigned short* __restrict__ pkWp,
                 unsigned short* __restrict__ xb,
                 int* __restrict__ cntI, int* __restrict__ slots) {
    const int b = blockIdx.x, tid = threadIdx.x;
    if (b < 48) {
        // pack W [DOUT][DIN] f32 -> bf16 B-fragment layout (16x16x32)
        int m = b >> 4;
        const float* W = (m == 0) ? Wl : (m == 1) ? Wr : Wp;
        unsigned short* pk = (m == 0) ? pkWl : (m == 1) ? pkWr : pkWp;
        int t2 = (b & 15) * 256 + tid;            // 0..4095
        int kt = t2 >> 10;
        int ct = (t2 >> 6) & 15;
        int l  = t2 & 63;
        int n  = ct * 16 + (l & 15);
        int kb = kt * 32 + (l >> 4) * 8;
        const float4* wp = (const float4*)(W + n * DIN + kb);
        float4 a = wp[0], c = wp[1];
        bf16x8 o;
        o[0]=(short)f2bf(a.x); o[1]=(short)f2bf(a.y); o[2]=(short)f2bf(a.z); o[3]=(short)f2bf(a.w);
        o[4]=(short)f2bf(c.x); o[5]=(short)f2bf(c.y); o[6]=(short)f2bf(c.z); o[7]=(short)f2bf(c.w);
        *(bf16x8*)(pk + (size_t)t2 * 8) = o;
    } else if (b < 6298) {
        // convert x f32 -> bf16, 8 elems/thread; (6250*256) == NN*16 exactly
        size_t i = (size_t)(b - 48) * 256 + tid;
        const float4* xp = (const float4*)x + i * 2;
        float4 a = xp[0], c = xp[1];
        bf16x8 o;
        o[0]=(short)f2bf(a.x); o[1]=(short)f2bf(a.y); o[2]=(short)f2bf(a.z); o[3]=(short)f2bf(a.w);
        o[4]=(short)f2bf(c.x); o[5]=(short)f2bf(c.y); o[6]=(short)f2bf(c.z); o[7]=(short)f2bf(c.w);
        *(bf16x8*)(xb + i * 8) = o;
    } else {
        // scatter edges into per-destination slot table; (2500*256) == NE exactly
        int e = (b - 6298) * 256 + tid;
        int src = ei[e], dst = ei[NE + e];
        int pos = atomicAdd(&cntI[dst], 1);
        if (pos < CAP) slots[(size_t)dst * CAP + pos] = src;
    }
}

// one wave per node: gather bf16 neighbor rows from slot table, mean, write bf16
__global__ __launch_bounds__(256)
void slot_aggregate(const unsigned short* __restrict__ xb, const int* __restrict__ slots,
                    const int* __restrict__ cntI, unsigned short* __restrict__ agb) {
    int w = threadIdx.x >> 6, l = threadIdx.x & 63;
    int node = blockIdx.x * 4 + w;
    if (node >= NN) return;
    int c = cntI[node];
    c = (c < CAP) ? c : CAP;
    const int* sl = slots + (size_t)node * CAP;
    float sx = 0.0f, sy = 0.0f;
    for (int j = 0; j < c; ++j) {
        int s = sl[j];
        unsigned u = *(const unsigned*)(xb + (size_t)s * DIN + l * 2);
        sx += bf2f_lo(u);
        sy += bf2f_hi(u);
    }
    float iv = 1.0f / fmaxf((float)c, 1.0f);
    unsigned short a0 = f2bf(sx * iv), a1 = f2bf(sy * iv);
    *(unsigned*)(agb + (size_t)node * DIN + l * 2) = ((unsigned)a1 << 16) | a0;
}

// 64 nodes/block, 4 waves; wave w owns cols [w*64, w*64+64) and stages row-quad rt=w.
// Stage bf16 A-frags into LDS via global_load_lds (no VGPR round-trip).
// Pass1: h = ag@Wl + x@Wr. Bias+LN+GELU in accumulator. Pass2: h += x@Wp. Store.
// NOTE: launch_bounds (256,2) — (256,4) caps unified VGPR+AGPR at 128/wave and
// spills the 64-reg accumulator to scratch (R5: WRITE_SIZE 239 MB vs 102 MB out).
__global__ __launch_bounds__(256, 2)
void fused_mfma_kernel(const unsigned short* __restrict__ xb,
                       const unsigned short* __restrict__ agb,
                       const unsigned short* __restrict__ pkWl,
                       const unsigned short* __restrict__ pkWr,
                       const unsigned short* __restrict__ pkWp,
                       const float* __restrict__ b_l, const float* __restrict__ gamma,
                       const float* __restrict__ beta, float* __restrict__ out) {
    __shared__ unsigned short xsPk[4 * 4 * 64 * 8];   // [rt][kt][l][8] bf16, 16 KB
    __shared__ unsigned short agPk[4 * 4 * 64 * 8];
    __shared__ float redS[4][64], redS2[4][64];
    __shared__ float muS[64], rsS[64];

    const int t = threadIdx.x;
    const int w = t >> 6, l = t & 63;
    const int base = blockIdx.x * 64;
    const int rlo = l & 15;
    const int kof = (l >> 4) * 8;

    // ---- stage: wave w loads row-quad rt=w for x and agg ----
    {
        int r = base + w * 16 + rlo;
        if (r >= NN) r = NN - 1;                       // dup row; discarded on store
        const unsigned short* gx = xb  + (size_t)r * DIN + kof;
        const unsigned short* ga = agb + (size_t)r * DIN + kof;
#pragma unroll
        for (int kt = 0; kt < 4; ++kt) {
            async16(&xsPk[(size_t)((w * 4 + kt) * 64) * 8], gx + kt * 32);
            async16(&agPk[(size_t)((w * 4 + kt) * 64) * 8], ga + kt * 32);
        }
    }
    __syncthreads();   // drains vmcnt before ds_read

    f32x4 h[4][4];
#pragma unroll
    for (int a = 0; a < 4; ++a)
#pragma unroll
        for (int b = 0; b < 4; ++b) h[a][b] = (f32x4)(0.0f);

    // ---- pass 1: h = ag@Wl + x@Wr ----
#pragma unroll
    for (int kt = 0; kt < 4; ++kt) {
        bf16x8 ax[4], ag[4];
#pragma unroll
        for (int rt = 0; rt < 4; ++rt) {
            size_t off = ((size_t)(rt * 4 + kt) * 64 + l) * 8;
            ax[rt] = *(const bf16x8*)&xsPk[off];
            ag[rt] = *(const bf16x8*)&agPk[off];
        }
#pragma unroll
        for (int ct = 0; ct < 4; ++ct) {
            size_t boff = ((size_t)(kt * 16 + w * 4 + ct) * 64 + l) * 8;
            bf16x8 bl = *(const bf16x8*)(pkWl + boff);
            bf16x8 br = *(const bf16x8*)(pkWr + boff);
#pragma unroll
            for (int rt = 0; rt < 4; ++rt) {
                h[rt][ct] = __builtin_amdgcn_mfma_f32_16x16x32_bf16(ag[rt], bl, h[rt][ct], 0, 0, 0);
                h[rt][ct] = __builtin_amdgcn_mfma_f32_16x16x32_bf16(ax[rt], br, h[rt][ct], 0, 0, 0);
            }
        }
    }

    // ---- bias + LN stats ----
    float bl4[4], gm4[4], bt4[4];
#pragma unroll
    for (int ct = 0; ct < 4; ++ct) {
        int n = w * 64 + ct * 16 + rlo;
        bl4[ct] = b_l[n]; gm4[ct] = gamma[n]; bt4[ct] = beta[n];
    }

#pragma unroll
    for (int rt = 0; rt < 4; ++rt) {
        float s[4] = {0, 0, 0, 0}, s2[4] = {0, 0, 0, 0};
#pragma unroll
        for (int ct = 0; ct < 4; ++ct)
#pragma unroll
            for (int j = 0; j < 4; ++j) {
                float v = h[rt][ct][j] + bl4[ct];
                h[rt][ct][j] = v;
                s[j] += v; s2[j] += v * v;
            }
#pragma unroll
        for (int o = 1; o < 16; o <<= 1) {
#pragma unroll
            for (int j = 0; j < 4; ++j) {
                s[j]  += __shfl_xor(s[j], o);
                s2[j] += __shfl_xor(s2[j], o);
            }
        }
        if (rlo == 0) {
#pragma unroll
            for (int j = 0; j < 4; ++j) {
                int row = rt * 16 + (l >> 4) * 4 + j;
                redS[w][row] = s[j]; redS2[w][row] = s2[j];
            }
        }
    }
    __syncthreads();

    if (t < 64) {
        float mu = (redS[0][t] + redS[1][t] + redS[2][t] + redS[3][t]) * (1.0f / DOUT);
        float m2 = (redS2[0][t] + redS2[1][t] + redS2[2][t] + redS2[3][t]) * (1.0f / DOUT);
        float var = m2 - mu * mu;
        muS[t] = mu;
        rsS[t] = rsqrtf(var + LN_EPS);
    }
    __syncthreads();

    // ---- LN + GELU into accumulator ----
#pragma unroll
    for (int rt = 0; rt < 4; ++rt) {
#pragma unroll
        for (int j = 0; j < 4; ++j) {
            int row = rt * 16 + (l >> 4) * 4 + j;
            float mu = muS[row], rs = rsS[row];
#pragma unroll
            for (int ct = 0; ct < 4; ++ct) {
                float v = h[rt][ct][j];
                float nrm = (v - mu) * rs * gm4[ct] + bt4[ct];
                h[rt][ct][j] = 0.5f * nrm * (1.0f + erff(nrm * 0.70710678118f));
            }
        }
    }

    // ---- pass 2: h += x@Wp (A-frags re-read from LDS) ----
#pragma unroll
    for (int kt = 0; kt < 4; ++kt) {
        bf16x8 ax[4];
#pragma unroll
        for (int rt = 0; rt < 4; ++rt) {
            size_t off = ((size_t)(rt * 4 + kt) * 64 + l) * 8;
            ax[rt] = *(const bf16x8*)&xsPk[off];
        }
#pragma unroll
        for (int ct = 0; ct < 4; ++ct) {
            size_t boff = ((size_t)(kt * 16 + w * 4 + ct) * 64 + l) * 8;
            bf16x8 bp = *(const bf16x8*)(pkWp + boff);
#pragma unroll
            for (int rt = 0; rt < 4; ++rt)
                h[rt][ct] = __builtin_amdgcn_mfma_f32_16x16x32_bf16(ax[rt], bp, h[rt][ct], 0, 0, 0);
        }
    }

    // ---- store ----
#pragma unroll
    for (int rt = 0; rt < 4; ++rt) {
#pragma unroll
        for (int j = 0; j < 4; ++j) {
            int row = rt * 16 + (l >> 4) * 4 + j;
            int r = base + row;
            if (r >= NN) continue;
#pragma unroll
            for (int ct = 0; ct < 4; ++ct) {
                int n = w * 64 + ct * 16 + rlo;
                out[(size_t)r * DOUT + n] = h[rt][ct][j];
            }
        }
    }
}

extern "C" void kernel_launch(void* const* d_in, const int* in_sizes, int n_in,
                              void* d_out, int out_size, void* d_ws, size_t ws_size,
                              hipStream_t stream) {
    const float* x      = (const float*)d_in[0];
    const int*   ei     = (const int*)d_in[1];
    const float* W_l    = (const float*)d_in[2];
    const float* b_l    = (const float*)d_in[3];
    const float* W_r    = (const float*)d_in[4];
    const float* gamma  = (const float*)d_in[5];
    const float* beta   = (const float*)d_in[6];
    const float* W_proj = (const float*)d_in[7];
    float* out = (float*)d_out;

    char* ws = (char*)d_ws;
    unsigned short* pkWl = (unsigned short*)(ws + WS_PKL);
    unsigned short* pkWr = (unsigned short*)(ws + WS_PKR);
    unsigned short* pkWp = (unsigned short*)(ws + WS_PKP);
    unsigned short* xb   = (unsigned short*)(ws + WS_XB);
    unsigned short* agb  = (unsigned short*)(ws + WS_AGB);
    int* cntI  = (int*)(ws + WS_CNTI);
    int* slots = (int*)(ws + WS_SLOT);

    hipMemsetAsync(cntI, 0, (size_t)NN * 4, stream);

    prep_kernel<<<8798, 256, 0, stream>>>(W_l, W_r, W_proj, x, ei,
                                          pkWl, pkWr, pkWp, xb, cntI, slots);

    slot_aggregate<<<(NN + 3) / 4, 256, 0, stream>>>(xb, slots, cntI, agb);

    fused_mfma_kernel<<<(NN + 63) / 64, 256, 0, stream>>>(
        xb, agb, pkWl, pkWr, pkWp, b_l, gamma, beta, out);
}

// Round 7
// 205.996 us; speedup vs baseline: 1.4839x; 1.0449x over previous
//
#include <hip/hip_runtime.h>
#include <cstdint>

#define NN 100000
#define NE 640000
#define DIN 128
#define DOUT 256
#define LN_EPS 1e-5f
#define CAP 64   // slots per node; P(deg>=64) ~ 1e-45 for Poisson(6.4)

typedef __attribute__((ext_vector_type(8))) short bf16x8;
typedef __attribute__((ext_vector_type(4))) float f32x4;

// ---- workspace layout (bytes) ----
#define WS_PKL  0u
#define WS_PKR  65536u
#define WS_PKP  131072u
#define WS_XB   196608u                              // [NN][128] bf16 = 25.6 MB
#define WS_AGB  (WS_XB + (size_t)NN * DIN * 2)       // [NN][128] bf16
#define WS_CNTI (WS_AGB + (size_t)NN * DIN * 2)      // [NN] int (memset 0 each call)
#define WS_SLOT (WS_CNTI + (size_t)NN * 4)           // [NN][CAP] int = 25.6 MB

static __device__ __forceinline__ unsigned short f2bf(float f) {
    unsigned u = __builtin_bit_cast(unsigned, f);
    u += 0x7FFFu + ((u >> 16) & 1u);          // round-to-nearest-even
    return (unsigned short)(u >> 16);
}
static __device__ __forceinline__ float bf2f_lo(unsigned u) {
    return __builtin_bit_cast(float, u << 16);
}
static __device__ __forceinline__ float bf2f_hi(unsigned u) {
    return __builtin_bit_cast(float, u & 0xFFFF0000u);
}

// async global->LDS, 16B per lane; lds base must be wave-uniform, g is per-lane
static __device__ __forceinline__ void async16(void* lds, const void* g) {
    __builtin_amdgcn_global_load_lds(
        (const __attribute__((address_space(1))) unsigned*)g,
        (__attribute__((address_space(3))) unsigned*)lds, 16, 0, 0);
}

// ---- one prep kernel: pack 3 weights + convert x->bf16 + scatter edges ----
// blocks [0,48): pack (b>>4 selects matrix); [48,6298): convert; [6298,8798): scatter
__global__ __launch_bounds__(256)
void prep_kernel(const float* __restrict__ Wl, const float* __restrict__ Wr,
                 const float* __restrict__ Wp, const float* __restrict__ x,
                 const int* __restrict__ ei,
                 unsigned short* __restrict__ pkWl, unsigned short* __restrict__ pkWr,
                 unsigned short* __restrict__ pkWp,
                 unsigned short* __restrict__ xb,
                 int* __restrict__ cntI, int* __restrict__ slots) {
    const int b = blockIdx.x, tid = threadIdx.x;
    if (b < 48) {
        // pack W [DOUT][DIN] f32 -> bf16 B-fragment layout (16x16x32)
        int m = b >> 4;
        const float* W = (m == 0) ? Wl : (m == 1) ? Wr : Wp;
        unsigned short* pk = (m == 0) ? pkWl : (m == 1) ? pkWr : pkWp;
        int t2 = (b & 15) * 256 + tid;            // 0..4095
        int kt = t2 >> 10;
        int ct = (t2 >> 6) & 15;
        int l  = t2 & 63;
        int n  = ct * 16 + (l & 15);
        int kb = kt * 32 + (l >> 4) * 8;
        const float4* wp = (const float4*)(W + n * DIN + kb);
        float4 a = wp[0], c = wp[1];
        bf16x8 o;
        o[0]=(short)f2bf(a.x); o[1]=(short)f2bf(a.y); o[2]=(short)f2bf(a.z); o[3]=(short)f2bf(a.w);
        o[4]=(short)f2bf(c.x); o[5]=(short)f2bf(c.y); o[6]=(short)f2bf(c.z); o[7]=(short)f2bf(c.w);
        *(bf16x8*)(pk + (size_t)t2 * 8) = o;
    } else if (b < 6298) {
        // convert x f32 -> bf16, 8 elems/thread; (6250*256) == NN*16 exactly
        size_t i = (size_t)(b - 48) * 256 + tid;
        const float4* xp = (const float4*)x + i * 2;
        float4 a = xp[0], c = xp[1];
        bf16x8 o;
        o[0]=(short)f2bf(a.x); o[1]=(short)f2bf(a.y); o[2]=(short)f2bf(a.z); o[3]=(short)f2bf(a.w);
        o[4]=(short)f2bf(c.x); o[5]=(short)f2bf(c.y); o[6]=(short)f2bf(c.z); o[7]=(short)f2bf(c.w);
        *(bf16x8*)(xb + i * 8) = o;
    } else {
        // scatter edges into per-destination slot table; (2500*256) == NE exactly
        int e = (b - 6298) * 256 + tid;
        int src = ei[e], dst = ei[NE + e];
        int pos = atomicAdd(&cntI[dst], 1);
        if (pos < CAP) slots[(size_t)dst * CAP + pos] = src;
    }
}

// one wave per node: gather bf16 neighbor rows from slot table, mean, write bf16
__global__ __launch_bounds__(256)
void slot_aggregate(const unsigned short* __restrict__ xb, const int* __restrict__ slots,
                    const int* __restrict__ cntI, unsigned short* __restrict__ agb) {
    int w = threadIdx.x >> 6, l = threadIdx.x & 63;
    int node = blockIdx.x * 4 + w;
    if (node >= NN) return;
    int c = cntI[node];
    c = (c < CAP) ? c : CAP;
    const int* sl = slots + (size_t)node * CAP;
    float sx = 0.0f, sy = 0.0f;
    for (int j = 0; j < c; ++j) {
        int s = sl[j];
        unsigned u = *(const unsigned*)(xb + (size_t)s * DIN + l * 2);
        sx += bf2f_lo(u);
        sy += bf2f_hi(u);
    }
    float iv = 1.0f / fmaxf((float)c, 1.0f);
    unsigned short a0 = f2bf(sx * iv), a1 = f2bf(sy * iv);
    *(unsigned*)(agb + (size_t)node * DIN + l * 2) = ((unsigned)a1 << 16) | a0;
}

// 32 nodes/block (NN == 3125*32 exactly), 4 waves; wave w owns cols [w*64,+64).
// Small tile -> h[2][4]=32 acc regs, ~17.5 KB LDS -> 4+ blocks/CU for latency
// hiding (R6 was 2 blocks/CU, latency-bound at 97 µs with 21 µs HBM floor).
__global__ __launch_bounds__(256, 4)
void fused_mfma_kernel(const unsigned short* __restrict__ xb,
                       const unsigned short* __restrict__ agb,
                       const unsigned short* __restrict__ pkWl,
                       const unsigned short* __restrict__ pkWr,
                       const unsigned short* __restrict__ pkWp,
                       const float* __restrict__ b_l, const float* __restrict__ gamma,
                       const float* __restrict__ beta, float* __restrict__ out) {
    __shared__ unsigned short xsPk[2 * 4 * 64 * 8];   // [rt][kt][l][8] bf16, 8 KB
    __shared__ unsigned short agPk[2 * 4 * 64 * 8];
    __shared__ float redS[4][32], redS2[4][32];
    __shared__ float muS[32], rsS[32];

    const int t = threadIdx.x;
    const int w = t >> 6, l = t & 63;
    const int base = blockIdx.x * 32;
    const int rlo = l & 15;
    const int kof = (l >> 4) * 8;

    // ---- stage: wave w loads (mat = w>>1, rt = w&1); 4 async16 each ----
    {
        int rt = w & 1;
        int r = base + rt * 16 + rlo;
        const unsigned short* g = ((w >> 1) ? agb : xb) + (size_t)r * DIN + kof;
        unsigned short* ldsb = (w >> 1) ? agPk : xsPk;
#pragma unroll
        for (int kt = 0; kt < 4; ++kt)
            async16(&ldsb[(size_t)((rt * 4 + kt) * 64) * 8], g + kt * 32);
    }
    __syncthreads();   // drains vmcnt before ds_read

    f32x4 h[2][4];
#pragma unroll
    for (int a = 0; a < 2; ++a)
#pragma unroll
        for (int b = 0; b < 4; ++b) h[a][b] = (f32x4)(0.0f);

    // ---- pass 1: h = ag@Wl + x@Wr ----
#pragma unroll
    for (int kt = 0; kt < 4; ++kt) {
        bf16x8 ax[2], ag[2];
#pragma unroll
        for (int rt = 0; rt < 2; ++rt) {
            size_t off = ((size_t)(rt * 4 + kt) * 64 + l) * 8;
            ax[rt] = *(const bf16x8*)&xsPk[off];
            ag[rt] = *(const bf16x8*)&agPk[off];
        }
#pragma unroll
        for (int ct = 0; ct < 4; ++ct) {
            size_t boff = ((size_t)(kt * 16 + w * 4 + ct) * 64 + l) * 8;
            bf16x8 bl = *(const bf16x8*)(pkWl + boff);
            bf16x8 br = *(const bf16x8*)(pkWr + boff);
#pragma unroll
            for (int rt = 0; rt < 2; ++rt) {
                h[rt][ct] = __builtin_amdgcn_mfma_f32_16x16x32_bf16(ag[rt], bl, h[rt][ct], 0, 0, 0);
                h[rt][ct] = __builtin_amdgcn_mfma_f32_16x16x32_bf16(ax[rt], br, h[rt][ct], 0, 0, 0);
            }
        }
    }

    // ---- bias + LN stats ----
    float bl4[4], gm4[4], bt4[4];
#pragma unroll
    for (int ct = 0; ct < 4; ++ct) {
        int n = w * 64 + ct * 16 + rlo;
        bl4[ct] = b_l[n]; gm4[ct] = gamma[n]; bt4[ct] = beta[n];
    }

#pragma unroll
    for (int rt = 0; rt < 2; ++rt) {
        float s[4] = {0, 0, 0, 0}, s2[4] = {0, 0, 0, 0};
#pragma unroll
        for (int ct = 0; ct < 4; ++ct)
#pragma unroll
            for (int j = 0; j < 4; ++j) {
                float v = h[rt][ct][j] + bl4[ct];
                h[rt][ct][j] = v;
                s[j] += v; s2[j] += v * v;
            }
#pragma unroll
        for (int o = 1; o < 16; o <<= 1) {
#pragma unroll
            for (int j = 0; j < 4; ++j) {
                s[j]  += __shfl_xor(s[j], o);
                s2[j] += __shfl_xor(s2[j], o);
            }
        }
        if (rlo == 0) {
#pragma unroll
            for (int j = 0; j < 4; ++j) {
                int row = rt * 16 + (l >> 4) * 4 + j;
                redS[w][row] = s[j]; redS2[w][row] = s2[j];
            }
        }
    }
    __syncthreads();

    if (t < 32) {
        float mu = (redS[0][t] + redS[1][t] + redS[2][t] + redS[3][t]) * (1.0f / DOUT);
        float m2 = (redS2[0][t] + redS2[1][t] + redS2[2][t] + redS2[3][t]) * (1.0f / DOUT);
        float var = m2 - mu * mu;
        muS[t] = mu;
        rsS[t] = rsqrtf(var + LN_EPS);
    }
    __syncthreads();

    // ---- LN + GELU into accumulator ----
#pragma unroll
    for (int rt = 0; rt < 2; ++rt) {
#pragma unroll
        for (int j = 0; j < 4; ++j) {
            int row = rt * 16 + (l >> 4) * 4 + j;
            float mu = muS[row], rs = rsS[row];
#pragma unroll
            for (int ct = 0; ct < 4; ++ct) {
                float v = h[rt][ct][j];
                float nrm = (v - mu) * rs * gm4[ct] + bt4[ct];
                h[rt][ct][j] = 0.5f * nrm * (1.0f + erff(nrm * 0.70710678118f));
            }
        }
    }

    // ---- pass 2: h += x@Wp (A-frags re-read from LDS) ----
#pragma unroll
    for (int kt = 0; kt < 4; ++kt) {
        bf16x8 ax[2];
#pragma unroll
        for (int rt = 0; rt < 2; ++rt) {
            size_t off = ((size_t)(rt * 4 + kt) * 64 + l) * 8;
            ax[rt] = *(const bf16x8*)&xsPk[off];
        }
#pragma unroll
        for (int ct = 0; ct < 4; ++ct) {
            size_t boff = ((size_t)(kt * 16 + w * 4 + ct) * 64 + l) * 8;
            bf16x8 bp = *(const bf16x8*)(pkWp + boff);
#pragma unroll
            for (int rt = 0; rt < 2; ++rt)
                h[rt][ct] = __builtin_amdgcn_mfma_f32_16x16x32_bf16(ax[rt], bp, h[rt][ct], 0, 0, 0);
        }
    }

    // ---- store ----
#pragma unroll
    for (int rt = 0; rt < 2; ++rt) {
#pragma unroll
        for (int j = 0; j < 4; ++j) {
            int row = rt * 16 + (l >> 4) * 4 + j;
            int r = base + row;
#pragma unroll
            for (int ct = 0; ct < 4; ++ct) {
                int n = w * 64 + ct * 16 + rlo;
                out[(size_t)r * DOUT + n] = h[rt][ct][j];
            }
        }
    }
}

extern "C" void kernel_launch(void* const* d_in, const int* in_sizes, int n_in,
                              void* d_out, int out_size, void* d_ws, size_t ws_size,
                              hipStream_t stream) {
    const float* x      = (const float*)d_in[0];
    const int*   ei     = (const int*)d_in[1];
    const float* W_l    = (const float*)d_in[2];
    const float* b_l    = (const float*)d_in[3];
    const float* W_r    = (const float*)d_in[4];
    const float* gamma  = (const float*)d_in[5];
    const float* beta   = (const float*)d_in[6];
    const float* W_proj = (const float*)d_in[7];
    float* out = (float*)d_out;

    char* ws = (char*)d_ws;
    unsigned short* pkWl = (unsigned short*)(ws + WS_PKL);
    unsigned short* pkWr = (unsigned short*)(ws + WS_PKR);
    unsigned short* pkWp = (unsigned short*)(ws + WS_PKP);
    unsigned short* xb   = (unsigned short*)(ws + WS_XB);
    unsigned short* agb  = (unsigned short*)(ws + WS_AGB);
    int* cntI  = (int*)(ws + WS_CNTI);
    int* slots = (int*)(ws + WS_SLOT);

    hipMemsetAsync(cntI, 0, (size_t)NN * 4, stream);

    prep_kernel<<<8798, 256, 0, stream>>>(W_l, W_r, W_proj, x, ei,
                                          pkWl, pkWr, pkWp, xb, cntI, slots);

    slot_aggregate<<<(NN + 3) / 4, 256, 0, stream>>>(xb, slots, cntI, agb);

    fused_mfma_kernel<<<NN / 32, 256, 0, stream>>>(
        xb, agb, pkWl, pkWr, pkWp, b_l, gamma, beta, out);
}